// Round 14
// baseline (158.782 us; speedup 1.0000x reference)
//
#include <hip/hip_runtime.h>

#define KDIM 64
#define VDIM 64
#define MDIM 2048
#define BDIM 512
#define INDIM 512
#define HDIM 192           // 2K+V
#define CIN 768            // IN + 2K + 2V
#define O_SIZE (BDIM*HDIM) // 98304
#define MH (MDIM/2)        // 1024 m's per half-block

typedef float f32x2 __attribute__((ext_vector_type(2)));

// ---- K1: per (b, half): partial scores + local softmax + partial PV ----
__global__ __launch_bounds__(512, 4)
void attn_partial_kernel(const float* __restrict__ x,
                         const float* __restrict__ hidden,
                         const float* __restrict__ content,
                         const float* __restrict__ key_mem,
                         const float* __restrict__ value_mem,
                         const float* __restrict__ W,
                         const float* __restrict__ bias,
                         float* __restrict__ out,
                         float* __restrict__ wnum,   // [1024][64]
                         float* __restrict__ wMS)    // [1024][2] (M,S)
{
    const int bh   = blockIdx.x;     // 0..1023
    const int b    = bh >> 1;
    const int h    = bh & 1;
    const int tid  = threadIdx.x;
    const int lane = tid & 63;
    const int wid  = tid >> 6;

    __shared__ __align__(16) float inp[CIN];       // 3 KB
    __shared__ float q[KDIM];
    __shared__ float red[8];
    __shared__ __align__(16) float attn_lds[MH];   // 4 KB (unnormalized exp)

    // ---- A1: stage concat input ----
    if (tid < INDIM) inp[tid] = x[(size_t)b*INDIM + tid];
    if (tid < HDIM)  inp[INDIM + tid] = fmaxf(hidden[(size_t)b*HDIM + tid], 0.f);
    if (tid < VDIM)  inp[INDIM + HDIM + tid] = content[(size_t)b*VDIM + tid];
    __syncthreads();

    // ---- A2: q = o[:,:64], 8 threads per output ----
    {
        const int j = tid >> 3;
        const int p = tid & 7;
        const float4* w4 = reinterpret_cast<const float4*>(W)
                           + (size_t)j * (CIN/4) + p * (CIN/32);
        const float4* i4 = reinterpret_cast<const float4*>(inp) + p * (CIN/32);
        float ax = 0.f, ay = 0.f, az = 0.f, aw = 0.f;
        #pragma unroll
        for (int r = 0; r < CIN/32; r += 8) {
            float4 wr[8];
            #pragma unroll
            for (int u = 0; u < 8; ++u) wr[u] = w4[r + u];
            #pragma unroll
            for (int u = 0; u < 8; ++u) {
                float4 v = i4[r + u];
                ax = fmaf(wr[u].x, v.x, ax);
                ay = fmaf(wr[u].y, v.y, ay);
                az = fmaf(wr[u].z, v.z, az);
                aw = fmaf(wr[u].w, v.w, aw);
            }
        }
        float pacc = (ax + ay) + (az + aw);
        pacc += __shfl_xor(pacc, 1);
        pacc += __shfl_xor(pacc, 2);
        pacc += __shfl_xor(pacc, 4);
        if (p == 0) {
            float o = pacc + bias[j];
            if (h == 0) out[(size_t)b*HDIM + j] = o;
            q[j] = o;
        }
    }
    __syncthreads();

    // ---- B: partial scores over this m-half, NT key stream ----
    // thread owns m_local = {2*tid, 2*tid+1}
    const f32x2* km2 = reinterpret_cast<const f32x2*>(
                           key_mem + (size_t)b*KDIM*MDIM + h*MH) + tid;
    float sx = 0.f, sy = 0.f;
    #pragma unroll 8
    for (int k = 0; k < KDIM; ++k) {
        float qk = q[k];
        f32x2 kk = __builtin_nontemporal_load(km2 + (size_t)k*(MDIM/2));
        sx = fmaf(qk, kk.x, sx);
        sy = fmaf(qk, kk.y, sy);
    }

    // ---- C: local softmax partial (M_h, S_h), exp kept unnormalized ----
    float mx = fmaxf(sx, sy);
    #pragma unroll
    for (int off = 32; off >= 1; off >>= 1)
        mx = fmaxf(mx, __shfl_xor(mx, off));
    if (lane == 0) red[wid] = mx;
    __syncthreads();
    float m_all = red[0];
    #pragma unroll
    for (int w = 1; w < 8; ++w) m_all = fmaxf(m_all, red[w]);

    float ex = __expf(sx - m_all);
    float ey = __expf(sy - m_all);
    float sum = ex + ey;
    #pragma unroll
    for (int off = 32; off >= 1; off >>= 1)
        sum += __shfl_xor(sum, off);
    __syncthreads();
    if (lane == 0) red[wid] = sum;
    __syncthreads();
    float total = 0.f;
    #pragma unroll
    for (int w = 0; w < 8; ++w) total += red[w];

    if (tid == 0) {
        wMS[2*bh]     = m_all;
        wMS[2*bh + 1] = total;
    }
    reinterpret_cast<float2*>(attn_lds)[tid] = make_float2(ex, ey);
    __syncthreads();

    // ---- D: partial PV over this m-half, cached value stream ----
    // wave owns 8 v's; per v: lane reads 4 float4 (16 floats of the 1024)
    const float4* vm4 = reinterpret_cast<const float4*>(
                            value_mem + (size_t)b*VDIM*MDIM + h*MH);
    const float4* a4  = reinterpret_cast<const float4*>(attn_lds);
    #pragma unroll
    for (int vi = 0; vi < 8; ++vi) {
        int v = wid*8 + vi;
        float px = 0.f, py = 0.f, pz = 0.f, pw = 0.f;
        #pragma unroll
        for (int i = 0; i < 4; ++i) {
            float4 vv = vm4[(size_t)v*(MDIM/4) + i*64 + lane];
            float4 aa = a4[i*64 + lane];
            px = fmaf(vv.x, aa.x, px);
            py = fmaf(vv.y, aa.y, py);
            pz = fmaf(vv.z, aa.z, pz);
            pw = fmaf(vv.w, aa.w, pw);
        }
        float p = (px + py) + (pz + pw);
        #pragma unroll
        for (int off = 32; off >= 1; off >>= 1)
            p += __shfl_xor(p, off);
        if (lane == 0) wnum[(size_t)bh*VDIM + v] = p;
    }

    // ---- E (h==0 only): remaining outputs o[:,64:192] ----
    if (h == 0) {
        const int jj = tid >> 2;
        const int j  = KDIM + jj;
        const int p  = tid & 3;
        const float4* w4 = reinterpret_cast<const float4*>(W)
                           + (size_t)j * (CIN/4) + p * (CIN/16);
        const float4* i4 = reinterpret_cast<const float4*>(inp) + p * (CIN/16);
        float ax = 0.f, ay = 0.f, az = 0.f, aw = 0.f;
        #pragma unroll
        for (int r = 0; r < CIN/16; r += 8) {
            float4 wr[8];
            #pragma unroll
            for (int u = 0; u < 8; ++u) wr[u] = w4[r + u];
            #pragma unroll
            for (int u = 0; u < 8; ++u) {
                float4 v = i4[r + u];
                ax = fmaf(wr[u].x, v.x, ax);
                ay = fmaf(wr[u].y, v.y, ay);
                az = fmaf(wr[u].z, v.z, az);
                aw = fmaf(wr[u].w, v.w, aw);
            }
        }
        float pacc = (ax + ay) + (az + aw);
        pacc += __shfl_xor(pacc, 1);
        pacc += __shfl_xor(pacc, 2);
        if (p == 0) out[(size_t)b*HDIM + j] = pacc + bias[j];
    }
}

// ---- K2: combine the two halves (flash-style) ----
__global__ __launch_bounds__(64)
void combine_kernel(const float* __restrict__ wnum,
                    const float* __restrict__ wMS,
                    float* __restrict__ out)
{
    const int b = blockIdx.x;
    const int v = threadIdx.x;
    const float M0 = wMS[4*b + 0], S0 = wMS[4*b + 1];
    const float M1 = wMS[4*b + 2], S1 = wMS[4*b + 3];
    const float M  = fmaxf(M0, M1);
    const float a0 = __expf(M0 - M), a1 = __expf(M1 - M);
    const float den = S0*a0 + S1*a1;
    const float num = wnum[(size_t)(2*b)*VDIM + v]*a0
                    + wnum[(size_t)(2*b + 1)*VDIM + v]*a1;
    out[O_SIZE + (size_t)b*VDIM + v] = num / den;
}

extern "C" void kernel_launch(void* const* d_in, const int* in_sizes, int n_in,
                              void* d_out, int out_size, void* d_ws, size_t ws_size,
                              hipStream_t stream) {
    const float* x         = (const float*)d_in[0];
    const float* hidden    = (const float*)d_in[1];
    const float* content   = (const float*)d_in[2];
    const float* key_mem   = (const float*)d_in[3];
    const float* value_mem = (const float*)d_in[4];
    const float* W         = (const float*)d_in[5];
    const float* bias      = (const float*)d_in[6];
    float* out  = (float*)d_out;
    float* wnum = (float*)d_ws;                  // 1024*64 floats = 256 KB
    float* wMS  = wnum + 1024*VDIM;              // 1024*2 floats

    attn_partial_kernel<<<dim3(2*BDIM), dim3(512), 0, stream>>>(
        x, hidden, content, key_mem, value_mem, W, bias, out, wnum, wMS);
    combine_kernel<<<dim3(BDIM), dim3(64), 0, stream>>>(wnum, wMS, out);
}

// Round 15
// 120.818 us; speedup vs baseline: 1.3142x; 1.3142x over previous
//
#include <hip/hip_runtime.h>

#define KDIM 64
#define VDIM 64
#define MDIM 2048
#define BDIM 512
#define INDIM 512
#define HDIM 192           // 2K+V
#define CIN 768            // IN + 2K + 2V
#define O_SIZE (BDIM*HDIM) // 98304

typedef float f32x4 __attribute__((ext_vector_type(4)));

__global__ __launch_bounds__(512, 4)
void memlinear_kernel(const float* __restrict__ x,
                      const float* __restrict__ hidden,
                      const float* __restrict__ content,
                      const float* __restrict__ key_mem,
                      const float* __restrict__ value_mem,
                      const float* __restrict__ W,
                      const float* __restrict__ bias,
                      float* __restrict__ out)
{
    const int b    = blockIdx.x;
    const int tid  = threadIdx.x;
    const int lane = tid & 63;
    const int wid  = tid >> 6;

    __shared__ __align__(16) float inp[CIN];       // 3 KB
    __shared__ float q[KDIM];
    __shared__ float red[8];
    __shared__ __align__(16) float attn_lds[MDIM]; // 8 KB

    // ---- Phase A1: stage concat input ----
    if (tid < INDIM) inp[tid] = x[(size_t)b*INDIM + tid];
    if (tid < HDIM)  inp[INDIM + tid] = fmaxf(hidden[(size_t)b*HDIM + tid], 0.f);
    if (tid < VDIM)  inp[INDIM + HDIM + tid] = content[(size_t)b*VDIM + tid];
    __syncthreads();

    // ---- Phase A2: q only (o[:,:64]), 8 threads per output ----
    {
        const int j = tid >> 3;        // 0..63
        const int p = tid & 7;         // part
        const float4* w4 = reinterpret_cast<const float4*>(W)
                           + (size_t)j * (CIN/4) + p * (CIN/32);
        const float4* i4 = reinterpret_cast<const float4*>(inp) + p * (CIN/32);
        float ax = 0.f, ay = 0.f, az = 0.f, aw = 0.f;
        #pragma unroll
        for (int r = 0; r < CIN/32; r += 8) {      // 24 float4, 3 rounds of 8
            float4 wr[8];
            #pragma unroll
            for (int u = 0; u < 8; ++u) wr[u] = w4[r + u];
            #pragma unroll
            for (int u = 0; u < 8; ++u) {
                float4 v = i4[r + u];
                ax = fmaf(wr[u].x, v.x, ax);
                ay = fmaf(wr[u].y, v.y, ay);
                az = fmaf(wr[u].z, v.z, az);
                aw = fmaf(wr[u].w, v.w, aw);
            }
        }
        float pacc = (ax + ay) + (az + aw);
        pacc += __shfl_xor(pacc, 1);
        pacc += __shfl_xor(pacc, 2);
        pacc += __shfl_xor(pacc, 4);
        if (p == 0) {
            float o = pacc + bias[j];
            out[(size_t)b*HDIM + j] = o;
            q[j] = o;
        }
    }
    __syncthreads();

    // ---- V-prefetch: wave's first 2 v-rows, issued BEFORE the key stream.
    // Cached loads (L3-resident values); no dependency on scores, so they
    // overlap all of phase B and are drained by phase C's first barrier.
    const float4* vm4 = reinterpret_cast<const float4*>(value_mem + (size_t)b*VDIM*MDIM);
    const int v0 = wid*8 + 0, v1 = wid*8 + 1;
    float4 vv0[8], vv1[8];
    #pragma unroll
    for (int i = 0; i < 8; ++i) vv0[i] = vm4[(size_t)v0*(MDIM/4) + i*64 + lane];
    #pragma unroll
    for (int i = 0; i < 8; ++i) vv1[i] = vm4[(size_t)v1*(MDIM/4) + i*64 + lane];

    // ---- Phase B: scores[m] = sum_k key_mem[b,k,m]*q[k], 4 m's/thread, NT ----
    const f32x4* km4 = reinterpret_cast<const f32x4*>(key_mem + (size_t)b*KDIM*MDIM);
    float sx = 0.f, sy = 0.f, sz = 0.f, sw = 0.f;
    #pragma unroll 8
    for (int k = 0; k < KDIM; ++k) {
        float qk = q[k];
        f32x4 kk = __builtin_nontemporal_load(km4 + (size_t)k*(MDIM/4) + tid);
        sx = fmaf(qk, kk.x, sx);
        sy = fmaf(qk, kk.y, sy);
        sz = fmaf(qk, kk.z, sz);
        sw = fmaf(qk, kk.w, sw);
    }

    // ---- Phase C: block softmax over m ----
    float mx = fmaxf(fmaxf(sx, sy), fmaxf(sz, sw));
    #pragma unroll
    for (int off = 32; off >= 1; off >>= 1)
        mx = fmaxf(mx, __shfl_xor(mx, off));
    if (lane == 0) red[wid] = mx;
    __syncthreads();
    float m_all = red[0];
    #pragma unroll
    for (int w = 1; w < 8; ++w) m_all = fmaxf(m_all, red[w]);

    float ex = __expf(sx - m_all);
    float ey = __expf(sy - m_all);
    float ez = __expf(sz - m_all);
    float ew = __expf(sw - m_all);
    float sum = (ex + ey) + (ez + ew);
    #pragma unroll
    for (int off = 32; off >= 1; off >>= 1)
        sum += __shfl_xor(sum, off);
    __syncthreads();
    if (lane == 0) red[wid] = sum;
    __syncthreads();
    float total = 0.f;
    #pragma unroll
    for (int w = 0; w < 8; ++w) total += red[w];
    float inv = 1.0f / total;

    reinterpret_cast<float4*>(attn_lds)[tid] =
        make_float4(ex*inv, ey*inv, ez*inv, ew*inv);
    __syncthreads();

    // ---- Phase D: content_new[v] = sum_m value_mem[b,v,m]*attn[m] ----
    // attn row hoisted to registers once per wave; first 2 v-rows use the
    // prefetched registers, remaining 6 stream cached as before.
    const float4* a4 = reinterpret_cast<const float4*>(attn_lds);
    float4 aa[8];
    #pragma unroll
    for (int i = 0; i < 8; ++i) aa[i] = a4[i*64 + lane];

    {   // v0 from prefetch
        float px = 0.f, py = 0.f, pz = 0.f, pw = 0.f;
        #pragma unroll
        for (int i = 0; i < 8; ++i) {
            px = fmaf(vv0[i].x, aa[i].x, px);
            py = fmaf(vv0[i].y, aa[i].y, py);
            pz = fmaf(vv0[i].z, aa[i].z, pz);
            pw = fmaf(vv0[i].w, aa[i].w, pw);
        }
        float p = (px + py) + (pz + pw);
        #pragma unroll
        for (int off = 32; off >= 1; off >>= 1) p += __shfl_xor(p, off);
        if (lane == 0) out[O_SIZE + (size_t)b*VDIM + v0] = p;
    }
    {   // v1 from prefetch
        float px = 0.f, py = 0.f, pz = 0.f, pw = 0.f;
        #pragma unroll
        for (int i = 0; i < 8; ++i) {
            px = fmaf(vv1[i].x, aa[i].x, px);
            py = fmaf(vv1[i].y, aa[i].y, py);
            pz = fmaf(vv1[i].z, aa[i].z, pz);
            pw = fmaf(vv1[i].w, aa[i].w, pw);
        }
        float p = (px + py) + (pz + pw);
        #pragma unroll
        for (int off = 32; off >= 1; off >>= 1) p += __shfl_xor(p, off);
        if (lane == 0) out[O_SIZE + (size_t)b*VDIM + v1] = p;
    }
    #pragma unroll
    for (int vi = 2; vi < 8; ++vi) {
        int v = wid*8 + vi;
        float px = 0.f, py = 0.f, pz = 0.f, pw = 0.f;
        #pragma unroll
        for (int i = 0; i < 8; ++i) {
            float4 vv = vm4[(size_t)v*(MDIM/4) + i*64 + lane];
            px = fmaf(vv.x, aa[i].x, px);
            py = fmaf(vv.y, aa[i].y, py);
            pz = fmaf(vv.z, aa[i].z, pz);
            pw = fmaf(vv.w, aa[i].w, pw);
        }
        float p = (px + py) + (pz + pw);
        #pragma unroll
        for (int off = 32; off >= 1; off >>= 1) p += __shfl_xor(p, off);
        if (lane == 0) out[O_SIZE + (size_t)b*VDIM + v] = p;
    }

    // ---- Phase E (tail): remaining outputs o[:,64:192], 4 threads/output ----
    {
        const int jj = tid >> 2;       // 0..127
        const int j  = KDIM + jj;      // 64..191
        const int p  = tid & 3;
        const float4* w4 = reinterpret_cast<const float4*>(W)
                           + (size_t)j * (CIN/4) + p * (CIN/16);
        const float4* i4 = reinterpret_cast<const float4*>(inp) + p * (CIN/16);
        float ax = 0.f, ay = 0.f, az = 0.f, aw = 0.f;
        #pragma unroll
        for (int r = 0; r < CIN/16; r += 8) {      // 48 float4, 6 rounds of 8
            float4 wr[8];
            #pragma unroll
            for (int u = 0; u < 8; ++u) wr[u] = w4[r + u];
            #pragma unroll
            for (int u = 0; u < 8; ++u) {
                float4 v = i4[r + u];
                ax = fmaf(wr[u].x, v.x, ax);
                ay = fmaf(wr[u].y, v.y, ay);
                az = fmaf(wr[u].z, v.z, az);
                aw = fmaf(wr[u].w, v.w, aw);
            }
        }
        float pacc = (ax + ay) + (az + aw);
        pacc += __shfl_xor(pacc, 1);
        pacc += __shfl_xor(pacc, 2);
        if (p == 0) out[(size_t)b*HDIM + j] = pacc + bias[j];
    }
}

extern "C" void kernel_launch(void* const* d_in, const int* in_sizes, int n_in,
                              void* d_out, int out_size, void* d_ws, size_t ws_size,
                              hipStream_t stream) {
    const float* x         = (const float*)d_in[0];
    const float* hidden    = (const float*)d_in[1];
    const float* content   = (const float*)d_in[2];
    const float* key_mem   = (const float*)d_in[3];
    const float* value_mem = (const float*)d_in[4];
    const float* W         = (const float*)d_in[5];
    const float* bias      = (const float*)d_in[6];
    float* out = (float*)d_out;

    memlinear_kernel<<<dim3(BDIM), dim3(512), 0, stream>>>(
        x, hidden, content, key_mem, value_mem, W, bias, out);
}

// Round 16
// 116.032 us; speedup vs baseline: 1.3684x; 1.0412x over previous
//
#include <hip/hip_runtime.h>

#define KDIM 64
#define VDIM 64
#define MDIM 2048
#define BDIM 512
#define INDIM 512
#define HDIM 192           // 2K+V
#define CIN 768            // IN + 2K + 2V
#define O_SIZE (BDIM*HDIM) // 98304

typedef float f32x4 __attribute__((ext_vector_type(4)));

__global__ __launch_bounds__(512, 4)
void memlinear_kernel(const float* __restrict__ x,
                      const float* __restrict__ hidden,
                      const float* __restrict__ content,
                      const float* __restrict__ key_mem,
                      const float* __restrict__ value_mem,
                      const float* __restrict__ W,
                      const float* __restrict__ bias,
                      float* __restrict__ out)
{
    const int b    = blockIdx.x;
    const int tid  = threadIdx.x;
    const int lane = tid & 63;
    const int wid  = tid >> 6;

    __shared__ __align__(16) float inp[CIN];       // 3 KB
    __shared__ float q[KDIM];
    __shared__ float red[8];
    __shared__ __align__(16) float attn_lds[MDIM]; // 8 KB

    // ---- Phase A1: stage concat input ----
    if (tid < INDIM) inp[tid] = x[(size_t)b*INDIM + tid];
    if (tid < HDIM)  inp[INDIM + tid] = fmaxf(hidden[(size_t)b*HDIM + tid], 0.f);
    if (tid < VDIM)  inp[INDIM + HDIM + tid] = content[(size_t)b*VDIM + tid];
    __syncthreads();

    // ---- Phase A2: q only (o[:,:64]), 8 threads per output -> short prologue ----
    {
        const int j = tid >> 3;        // 0..63
        const int p = tid & 7;         // part
        const float4* w4 = reinterpret_cast<const float4*>(W)
                           + (size_t)j * (CIN/4) + p * (CIN/32);
        const float4* i4 = reinterpret_cast<const float4*>(inp) + p * (CIN/32);
        float ax = 0.f, ay = 0.f, az = 0.f, aw = 0.f;
        #pragma unroll
        for (int r = 0; r < CIN/32; r += 8) {      // 24 float4, 3 rounds of 8
            float4 wr[8];
            #pragma unroll
            for (int u = 0; u < 8; ++u) wr[u] = w4[r + u];
            #pragma unroll
            for (int u = 0; u < 8; ++u) {
                float4 v = i4[r + u];
                ax = fmaf(wr[u].x, v.x, ax);
                ay = fmaf(wr[u].y, v.y, ay);
                az = fmaf(wr[u].z, v.z, az);
                aw = fmaf(wr[u].w, v.w, aw);
            }
        }
        float pacc = (ax + ay) + (az + aw);
        pacc += __shfl_xor(pacc, 1);
        pacc += __shfl_xor(pacc, 2);
        pacc += __shfl_xor(pacc, 4);
        if (p == 0) {
            float o = pacc + bias[j];
            out[(size_t)b*HDIM + j] = o;
            q[j] = o;
        }
    }
    __syncthreads();

    // ---- Phase B: scores[m] = sum_k key_mem[b,k,m]*q[k], 4 m's/thread, NT ----
    const f32x4* km4 = reinterpret_cast<const f32x4*>(key_mem + (size_t)b*KDIM*MDIM);
    float sx = 0.f, sy = 0.f, sz = 0.f, sw = 0.f;
    #pragma unroll 8
    for (int k = 0; k < KDIM; ++k) {
        float qk = q[k];
        f32x4 kk = __builtin_nontemporal_load(km4 + (size_t)k*(MDIM/4) + tid);
        sx = fmaf(qk, kk.x, sx);
        sy = fmaf(qk, kk.y, sy);
        sz = fmaf(qk, kk.z, sz);
        sw = fmaf(qk, kk.w, sw);
    }

    // ---- Phase C: block softmax over m ----
    float mx = fmaxf(fmaxf(sx, sy), fmaxf(sz, sw));
    #pragma unroll
    for (int off = 32; off >= 1; off >>= 1)
        mx = fmaxf(mx, __shfl_xor(mx, off));
    if (lane == 0) red[wid] = mx;
    __syncthreads();
    float m_all = red[0];
    #pragma unroll
    for (int w = 1; w < 8; ++w) m_all = fmaxf(m_all, red[w]);

    float ex = __expf(sx - m_all);
    float ey = __expf(sy - m_all);
    float ez = __expf(sz - m_all);
    float ew = __expf(sw - m_all);
    float sum = (ex + ey) + (ez + ew);
    #pragma unroll
    for (int off = 32; off >= 1; off >>= 1)
        sum += __shfl_xor(sum, off);
    __syncthreads();
    if (lane == 0) red[wid] = sum;
    __syncthreads();
    float total = 0.f;
    #pragma unroll
    for (int w = 0; w < 8; ++w) total += red[w];
    float inv = 1.0f / total;

    reinterpret_cast<float4*>(attn_lds)[tid] =
        make_float4(ex*inv, ey*inv, ez*inv, ew*inv);
    __syncthreads();

    // ---- Phase D: content_new[v] = sum_m value_mem[b,v,m]*attn[m] ----
    // value_mem loads CACHED (L3-resident across graph replays); keys were NT
    // so they stream past without evicting value lines.
    const float4* vm4 = reinterpret_cast<const float4*>(value_mem + (size_t)b*VDIM*MDIM);
    const float4* a4  = reinterpret_cast<const float4*>(attn_lds);
    #pragma unroll
    for (int vi = 0; vi < 8; ++vi) {
        int v = wid*8 + vi;
        float px = 0.f, py = 0.f, pz = 0.f, pw = 0.f;
        #pragma unroll
        for (int i = 0; i < 8; ++i) {
            float4 vv = vm4[(size_t)v*(MDIM/4) + i*64 + lane];
            float4 aa = a4[i*64 + lane];
            px = fmaf(vv.x, aa.x, px);
            py = fmaf(vv.y, aa.y, py);
            pz = fmaf(vv.z, aa.z, pz);
            pw = fmaf(vv.w, aa.w, pw);
        }
        float p = (px + py) + (pz + pw);
        #pragma unroll
        for (int off = 32; off >= 1; off >>= 1)
            p += __shfl_xor(p, off);
        if (lane == 0) out[O_SIZE + (size_t)b*VDIM + v] = p;
    }

    // ---- Phase E (tail): remaining outputs o[:,64:192], 4 threads/output ----
    {
        const int jj = tid >> 2;       // 0..127
        const int j  = KDIM + jj;      // 64..191
        const int p  = tid & 3;
        const float4* w4 = reinterpret_cast<const float4*>(W)
                           + (size_t)j * (CIN/4) + p * (CIN/16);
        const float4* i4 = reinterpret_cast<const float4*>(inp) + p * (CIN/16);
        float ax = 0.f, ay = 0.f, az = 0.f, aw = 0.f;
        #pragma unroll
        for (int r = 0; r < CIN/16; r += 8) {      // 48 float4, 6 rounds of 8
            float4 wr[8];
            #pragma unroll
            for (int u = 0; u < 8; ++u) wr[u] = w4[r + u];
            #pragma unroll
            for (int u = 0; u < 8; ++u) {
                float4 v = i4[r + u];
                ax = fmaf(wr[u].x, v.x, ax);
                ay = fmaf(wr[u].y, v.y, ay);
                az = fmaf(wr[u].z, v.z, az);
                aw = fmaf(wr[u].w, v.w, aw);
            }
        }
        float pacc = (ax + ay) + (az + aw);
        pacc += __shfl_xor(pacc, 1);
        pacc += __shfl_xor(pacc, 2);
        if (p == 0) out[(size_t)b*HDIM + j] = pacc + bias[j];
    }
}

extern "C" void kernel_launch(void* const* d_in, const int* in_sizes, int n_in,
                              void* d_out, int out_size, void* d_ws, size_t ws_size,
                              hipStream_t stream) {
    const float* x         = (const float*)d_in[0];
    const float* hidden    = (const float*)d_in[1];
    const float* content   = (const float*)d_in[2];
    const float* key_mem   = (const float*)d_in[3];
    const float* value_mem = (const float*)d_in[4];
    const float* W         = (const float*)d_in[5];
    const float* bias      = (const float*)d_in[6];
    float* out = (float*)d_out;

    memlinear_kernel<<<dim3(BDIM), dim3(512), 0, stream>>>(
        x, hidden, content, key_mem, value_mem, W, bias, out);
}